// Round 10
// baseline (1652.039 us; speedup 1.0000x reference)
//
#include <hip/hip_runtime.h>

// ---------------- problem constants ----------------
#define T_TOK 8192          // B*S tokens
#define HID   2048
#define FFN_D 4096
#define NEXP  8
#define BM    128           // GEMM M tile (both GEMMs)
#define CAP_ROWS (T_TOK*2 + 256)         // 16640
#define MAX_TILES (T_TOK*2/BM + NEXP)    // 136 = 17*8
#define NB_UP2  (32*MAX_TILES)           // 4352 GEMM blocks in up launch (17*256 exact)
#define CVT_BLKS2 16384                  // fused w2-cvt blocks in up launch (512 thr * 8)
#define RT_BLKS  2048                    // route blocks in fused front launch
#define FCVT_BLKS 4096                   // w1/w3 cvt tail blocks in front launch
#define NT_K  32                         // K-tiles in up (2048/64)
#define WDELTA ((u32)(NEXP*(size_t)FFN_D*HID))   // elems between w1b and w3b

typedef unsigned short u16;
typedef unsigned int   u32;
typedef __attribute__((ext_vector_type(8))) u16    u16x8;
typedef __attribute__((ext_vector_type(8))) __bf16 bf16x8;
typedef __attribute__((ext_vector_type(4))) __bf16 bf16x4;
typedef __attribute__((ext_vector_type(4))) float  f32x4;

// meta[] int layout inside ws
#define M_CNT 0
#define M_CUR 8
#define M_OFF 16
#define M_NT  24
#define M_TEXP 32      // [136]
#define M_TM0  192     // [136]

__device__ __forceinline__ u16 f2bf(float f){   // RNE f32 -> bf16
  u32 u = __float_as_uint(f);
  u += 0x7FFFu + ((u >> 16) & 1u);
  return (u16)(u >> 16);
}
__device__ __forceinline__ float bf2f(u16 v){
  return __uint_as_float(((u32)v) << 16);
}

__device__ __forceinline__ void gload16(const void* g, void* l){
  __builtin_amdgcn_global_load_lds((const __attribute__((address_space(1))) u32*)g,
                                   (__attribute__((address_space(3))) u32*)l, 16, 0, 0);
}

__device__ __forceinline__ bf16x8 cvt8(float4 v0, float4 v1){
  bf16x8 o;
  o[0]=(__bf16)v0.x; o[1]=(__bf16)v0.y; o[2]=(__bf16)v0.z; o[3]=(__bf16)v0.w;
  o[4]=(__bf16)v1.x; o[5]=(__bf16)v1.y; o[6]=(__bf16)v1.z; o[7]=(__bf16)v1.w;
  return o;
}

// ---------------- f32 -> bf16 stream convert (w2 fallback only) ----------------
__global__ __launch_bounds__(256) void moe_cvt(const float* __restrict__ src,
                                               u16* __restrict__ dst){
  size_t i = ((size_t)blockIdx.x * 256 + threadIdx.x) * 8;
  float4 v0 = *(const float4*)(src + i);
  float4 v1 = *(const float4*)(src + i + 4);
  *(bf16x8*)(dst + i) = cvt8(v0, v1);
}

// ---------------- fused front: routing + x->bf16 + w1/w3->bf16 ----------------
__global__ __launch_bounds__(256) void moe_route(const float* __restrict__ x,
                                                 const float* __restrict__ gw,
                                                 int* __restrict__ meta,
                                                 int* __restrict__ tok_top,
                                                 float* __restrict__ tok_wt,
                                                 u16* __restrict__ xb,
                                                 const float* __restrict__ w1,
                                                 u16* __restrict__ w1b,
                                                 const float* __restrict__ w3,
                                                 u16* __restrict__ w3b){
  if (blockIdx.x >= RT_BLKS){
    const size_t NELEM = (size_t)NEXP * FFN_D * HID;
    const size_t STR   = (size_t)FCVT_BLKS * 256 * 8;
    size_t i = ((size_t)(blockIdx.x - RT_BLKS) * 256 + threadIdx.x) * 8;
    for (; i < NELEM; i += STR){
      float4 a0 = *(const float4*)(w1 + i);
      float4 a1 = *(const float4*)(w1 + i + 4);
      *(bf16x8*)(w1b + i) = cvt8(a0, a1);
      float4 b0 = *(const float4*)(w3 + i);
      float4 b1 = *(const float4*)(w3 + i + 4);
      *(bf16x8*)(w3b + i) = cvt8(b0, b1);
    }
    return;
  }

  const int wid  = threadIdx.x >> 6;
  const int lane = threadIdx.x & 63;
  const int tok  = blockIdx.x * 4 + wid;
  const float* xr = x  + (size_t)tok * HID;
  u16*         xw = xb + (size_t)tok * HID;

  float s[NEXP];
  #pragma unroll
  for (int e=0;e<NEXP;e++) s[e]=0.f;

  for (int k = lane*4; k < HID; k += 256){
    const float4 xv = *(const float4*)(xr + k);
    bf16x4 xo;
    xo[0]=(__bf16)xv.x; xo[1]=(__bf16)xv.y; xo[2]=(__bf16)xv.z; xo[3]=(__bf16)xv.w;
    *(bf16x4*)(xw + k) = xo;
    #pragma unroll
    for (int e=0;e<NEXP;e++){
      const float4 g = *(const float4*)(gw + e*HID + k);
      s[e] += xv.x*g.x + xv.y*g.y + xv.z*g.z + xv.w*g.w;
    }
  }
  #pragma unroll
  for (int o=32;o;o>>=1){
    #pragma unroll
    for (int e=0;e<NEXP;e++) s[e] += __shfl_xor(s[e], o);
  }
  if (lane==0){
    float m1 = s[0]; int a = 0;
    #pragma unroll
    for (int e=1;e<NEXP;e++) if (s[e] > m1){ m1 = s[e]; a = e; }
    float m2 = -3.0e38f; int b = 0;
    #pragma unroll
    for (int e=0;e<NEXP;e++) if (e != a && s[e] > m2){ m2 = s[e]; b = e; }
    const float r  = __expf(m2 - m1);
    const float wa = 1.f / (1.f + r);
    tok_top[tok*2]   = a;  tok_top[tok*2+1] = b;
    tok_wt[tok*2]    = wa; tok_wt[tok*2+1]  = r * wa;
    atomicAdd(&meta[M_CNT + a], 1);
    atomicAdd(&meta[M_CNT + b], 1);
  }
}

// ---------------- prefix + tile table ----------------
__global__ void moe_prefix(int* __restrict__ meta){
  if (threadIdx.x != 0 || blockIdx.x != 0) return;
  int off = 0, nt = 0;
  for (int e=0;e<NEXP;e++){
    const int c = meta[M_CNT + e];
    meta[M_OFF + e] = off;
    meta[M_CUR + e] = off;
    const int ntE = (c + BM - 1) / BM;
    for (int i=0;i<ntE;i++){ meta[M_TEXP + nt] = e; meta[M_TM0 + nt] = off + i*BM; nt++; }
    off += c;
  }
  meta[M_NT] = nt;
}

// ---------------- scatter (records pos_of aliased on tok_wt) ----------------
__global__ __launch_bounds__(256) void moe_scatter(const int* __restrict__ tok_top,
                                                   float* __restrict__ tok_wt,
                                                   int* __restrict__ meta,
                                                   int* __restrict__ row_tok,
                                                   float* __restrict__ row_w){
  const int i = blockIdx.x * 256 + threadIdx.x;
  const int e = tok_top[i];
  const float w = tok_wt[i];
  const int pos = atomicAdd(&meta[M_CUR + e], 1);
  row_tok[pos] = i >> 1;
  row_w[pos]   = w;
  ((int*)tok_wt)[i] = pos;
}

// ================= up-GEMM: triple-buffered counted-vmcnt pipeline =================
// 512 threads, 8 waves (2M x 4N). BM=128 gathered rows, 128 output cols.
// B tile = 256 LDS rows: group grp=wn (32 cols each); rows [grp*64, grp*64+32) = w1 cols,
// [grp*64+32, grp*64+64) = w3 cols -> each thread's acc holds G (ni 0,1) AND U (ni 2,3).
// LDS 3 x (A 16KB + B 32KB) = 144 KB. Tile k issues t(k+2) loads; end-of-tile waits
// vmcnt(6) (t(k+1) complete, t(k+2) in flight) + raw s_barrier. Swizzle pc = c ^ (r&7).
__global__ __launch_bounds__(512,2) void moe_up_p3(
    const u16* __restrict__ xb, const u16* __restrict__ w1b,
    u16* __restrict__ act, const int* __restrict__ meta,
    const int* __restrict__ row_tok, const float* __restrict__ row_w,
    const float* __restrict__ w2, u16* __restrict__ w2b){
  if (blockIdx.x >= NB_UP2){
    const size_t base = ((size_t)(blockIdx.x - NB_UP2)) * 4096 + (size_t)threadIdx.x * 8;
    float4 v0 = *(const float4*)(w2 + base);
    float4 v1 = *(const float4*)(w2 + base + 4);
    *(bf16x8*)(w2b + base) = cvt8(v0, v1);
    return;
  }
  const int b    = blockIdx.x;
  const int q    = b >> 3;
  const int tile = q >> 2;                     // 0..135
  const int n0   = ((b & 7) + 8*(q & 3)) * 128;
  if (tile >= meta[M_NT]) return;
  const int e      = meta[M_TEXP + tile];
  const int m0     = meta[M_TM0 + tile];
  const int rowEnd = meta[M_OFF + e] + meta[M_CNT + e];

  __shared__ u16 As3[3][128*64];   // 3 x 16 KB
  __shared__ u16 Bs3[3][256*64];   // 3 x 32 KB

  const int t    = threadIdx.x;
  const int lane = t & 63;
  const int wid  = t >> 6;        // 0..7
  const int wm   = wid >> 2;      // 0..1 -> 64-row band
  const int wn   = wid & 3;       // 0..3 -> 32-col group
  const int lr = lane & 15;
  const int lq = lane >> 4;

  // A staging: 2 chunks/thread (1024 chunks = 128 rows x 8)
  u32 aoff[2];
  #pragma unroll
  for (int i=0;i<2;i++){
    const int g  = i*512 + t;
    const int r  = g >> 3;          // 0..127
    const int pc = g & 7;
    aoff[i] = (u32)row_tok[m0 + r] * HID + (u32)((pc ^ (r & 7)) * 8);
  }
  // B staging: 4 chunks/thread (2048 chunks = 256 rows x 8); w3 = w1b + WDELTA
  const u32 eW = (u32)e * (u32)(FFN_D*HID);
  u32 boff[4];
  #pragma unroll
  for (int i=0;i<4;i++){
    const int g   = i*512 + t;
    const int r   = g >> 3;         // 0..255
    const int pc  = g & 7;
    const int grp = r >> 6;         // 0..3
    const int win = r & 63;
    const u32 half = (u32)(win >> 5);          // 0 = w1, 1 = w3
    const int col = n0 + grp*32 + (win & 31);
    boff[i] = eW + half*WDELTA + (u32)col * HID + (u32)((pc ^ (r & 7)) * 8);
  }

#define UP_STAGE(AD, BD, KK) do {                                     \
    gload16(xb  + aoff[0] + (KK), (AD) + (size_t)(0*512 + wid*64)*8); \
    gload16(xb  + aoff[1] + (KK), (AD) + (size_t)(1*512 + wid*64)*8); \
    gload16(w1b + boff[0] + (KK), (BD) + (size_t)(0*512 + wid*64)*8); \
    gload16(w1b + boff[1] + (KK), (BD) + (size_t)(1*512 + wid*64)*8); \
    gload16(w1b + boff[2] + (KK), (BD) + (size_t)(2*512 + wid*64)*8); \
    gload16(w1b + boff[3] + (KK), (BD) + (size_t)(3*512 + wid*64)*8); \
  } while(0)

  f32x4 acc[4][4];
  #pragma unroll
  for (int i=0;i<4;i++){
    #pragma unroll
    for (int j=0;j<4;j++) acc[i][j]=(f32x4)0.f;
  }

  u16 *Ac = As3[0], *An = As3[1], *Af = As3[2];
  u16 *Bc = Bs3[0], *Bn = Bs3[1], *Bf = Bs3[2];

  // prologue: stage tiles 0 and 1; wait tile 0 (6 of 12 outstanding)
  UP_STAGE(Ac, Bc, 0);
  UP_STAGE(An, Bn, 64);
  asm volatile("s_waitcnt vmcnt(6)" ::: "memory");
  __builtin_amdgcn_s_barrier();
  asm volatile("" ::: "memory");

  for (int k = 0; k < NT_K; ++k){
    if (k < NT_K-2) UP_STAGE(Af, Bf, (k+2)*64);   // t(k+2) flies across 2 barriers

    #pragma unroll
    for (int ks=0; ks<2; ks++){
      const int c = ks*4 + lq;
      bf16x8 a[4], bb[4];
      #pragma unroll
      for (int mi=0;mi<4;mi++){
        const int rA = wm*64 + mi*16 + lr;
        a[mi] = *(const bf16x8*)(Ac + rA*64 + (c ^ (rA&7))*8);
      }
      #pragma unroll
      for (int ni=0;ni<4;ni++){
        const int rB = wn*64 + (ni&1)*16 + (ni>>1)*32;
        bb[ni] = *(const bf16x8*)(Bc + (rB + lr)*64 + (c ^ ((rB + lr)&7))*8);
      }
      __builtin_amdgcn_s_setprio(1);
      #pragma unroll
      for (int mi=0;mi<4;mi++){
        #pragma unroll
        for (int ni=0;ni<4;ni++)
          acc[mi][ni] = __builtin_amdgcn_mfma_f32_16x16x32_bf16(a[mi], bb[ni], acc[mi][ni],0,0,0);
      }
      __builtin_amdgcn_s_setprio(0);
    }

    if (k < NT_K-2)      asm volatile("s_waitcnt vmcnt(6)" ::: "memory");
    else if (k == NT_K-2) asm volatile("s_waitcnt vmcnt(0)" ::: "memory");
    if (k < NT_K-1){
      __builtin_amdgcn_s_barrier();
      asm volatile("" ::: "memory");
      u16* tA = Ac; Ac = An; An = Af; Af = tA;
      u16* tB = Bc; Bc = Bn; Bn = Bf; Bf = tB;
    }
  }
#undef UP_STAGE

  // epilogue: act[pos][n] = bf16(relu(G)*U*rw); G = acc[mi][ci], U = acc[mi][ci+2]
  const int l4 = lq * 4;
  #pragma unroll
  for (int mi=0;mi<4;mi++){
    #pragma unroll
    for (int r=0;r<4;r++){
      const int pos = m0 + wm*64 + mi*16 + l4 + r;
      if (pos < rowEnd){
        const float rw = row_w[pos];
        #pragma unroll
        for (int ci=0;ci<2;ci++){
          const int n = n0 + wn*32 + ci*16 + lr;
          const float g = acc[mi][ci][r];
          const float u = acc[mi][ci+2][r];
          act[(size_t)pos * FFN_D + n] = f2bf(fmaxf(g, 0.f) * u * rw);
        }
      }
    }
  }
}

// ================= down-GEMM (proven 128x128) + XCD swizzle, no atomics =================
__global__ __launch_bounds__(256,2) void moe_down_f(
    const u16* __restrict__ act, const u16* __restrict__ w2b,
    u16* __restrict__ part, const int* __restrict__ meta){
  const int b    = blockIdx.x;
  const int q    = b >> 3;
  const int tile = q >> 1;
  const int n0   = ((b & 7) + 8*(q & 1)) * 128;
  if (tile >= meta[M_NT]) return;
  const int e      = meta[M_TEXP + tile];
  const int m0     = meta[M_TM0 + tile];
  const int rowEnd = meta[M_OFF + e] + meta[M_CNT + e];

  __shared__ u16 As[128*64];   // 16 KB
  __shared__ u16 Bs[128*64];   // 16 KB

  const int t    = threadIdx.x;
  const int lane = t & 63;
  const int wid  = t >> 6;
  const int wm   = wid >> 1, wn = wid & 1;
  const int lr = lane & 15;
  const int lq = lane >> 4;

  u32 aoff[4], boff[4];
  const u16* w2e = w2b + (size_t)e * HID * FFN_D;
  #pragma unroll
  for (int i=0;i<4;i++){
    const int g  = i*256 + t;
    const int r  = g >> 3;           // 0..127
    const int pc = g & 7;
    const int c8 = (pc ^ (r & 7)) * 8;
    aoff[i] = (u32)(m0 + r) * FFN_D + (u32)c8;
    boff[i] = (u32)(n0 + r) * FFN_D + (u32)c8;
  }

  f32x4 acc[4][4];
  #pragma unroll
  for (int i=0;i<4;i++){
    #pragma unroll
    for (int j=0;j<4;j++) acc[i][j]=(f32x4)0.f;
  }

  for (int kk = 0; kk < FFN_D; kk += 64){
    __syncthreads();
    #pragma unroll
    for (int i=0;i<4;i++)
      gload16(act + aoff[i] + kk, As + (size_t)(i*256 + wid*64)*8);
    #pragma unroll
    for (int i=0;i<4;i++)
      gload16(w2e + boff[i] + kk, Bs + (size_t)(i*256 + wid*64)*8);
    __syncthreads();

    #pragma unroll
    for (int ks=0; ks<2; ks++){
      const int c = ks*4 + lq;
      bf16x8 a[4], bb[4];
      #pragma unroll
      for (int mi=0;mi<4;mi++){
        const int r = wm*64 + mi*16 + lr;
        a[mi] = *(const bf16x8*)(As + r*64 + (c ^ (r&7))*8);
      }
      #pragma unroll
      for (int ni=0;ni<4;ni++){
        const int r = wn*64 + ni*16 + lr;
        bb[ni] = *(const bf16x8*)(Bs + r*64 + (c ^ (r&7))*8);
      }
      #pragma unroll
      for (int mi=0;mi<4;mi++){
        #pragma unroll
        for (int ni=0;ni<4;ni++)
          acc[mi][ni] = __builtin_amdgcn_mfma_f32_16x16x32_bf16(a[mi], bb[ni], acc[mi][ni],0,0,0);
      }
    }
  }

  const int l4 = lq * 4;
  #pragma unroll
  for (int mi=0;mi<4;mi++){
    #pragma unroll
    for (int r=0;r<4;r++){
      const int pos = m0 + wm*64 + mi*16 + l4 + r;
      if (pos < rowEnd){
        u16* prow = part + (size_t)pos * HID;
        #pragma unroll
        for (int ni=0;ni<4;ni++){
          const int n = n0 + wn*64 + ni*16 + lr;
          prow[n] = f2bf(acc[mi][ni][r]);
        }
      }
    }
  }
}

// ---------------- combine: out[tok] = part[p0] + part[p1] ----------------
__global__ __launch_bounds__(256) void moe_combine(const u16* __restrict__ part,
                                                   const int* __restrict__ pos_of,
                                                   float* __restrict__ out){
  const int tok = blockIdx.x;
  const int p0 = pos_of[tok*2];
  const int p1 = pos_of[tok*2+1];
  const int h = threadIdx.x * 8;
  const u16x8 a = *(const u16x8*)(part + (size_t)p0 * HID + h);
  const u16x8 b = *(const u16x8*)(part + (size_t)p1 * HID + h);
  float4 o0, o1;
  o0.x = bf2f(a[0]) + bf2f(b[0]);
  o0.y = bf2f(a[1]) + bf2f(b[1]);
  o0.z = bf2f(a[2]) + bf2f(b[2]);
  o0.w = bf2f(a[3]) + bf2f(b[3]);
  o1.x = bf2f(a[4]) + bf2f(b[4]);
  o1.y = bf2f(a[5]) + bf2f(b[5]);
  o1.z = bf2f(a[6]) + bf2f(b[6]);
  o1.w = bf2f(a[7]) + bf2f(b[7]);
  float* orow = out + (size_t)tok * HID + h;
  *(float4*)orow = o0;
  *(float4*)(orow + 4) = o1;
}

// ---------------- host ----------------
extern "C" void kernel_launch(void* const* d_in, const int* in_sizes, int n_in,
                              void* d_out, int out_size, void* d_ws, size_t ws_size,
                              hipStream_t stream) {
  const float* x  = (const float*)d_in[0];
  const float* gw = (const float*)d_in[1];
  const float* w1 = (const float*)d_in[2];
  const float* w2 = (const float*)d_in[3];
  const float* w3 = (const float*)d_in[4];
  float* out = (float*)d_out;

  const size_t OFF_ROWTOK = 4096;
  const size_t OFF_ROWW   = OFF_ROWTOK + (size_t)CAP_ROWS*4;
  const size_t OFF_TOP    = OFF_ROWW  + (size_t)CAP_ROWS*4;
  const size_t OFF_TOKW   = OFF_TOP   + (size_t)T_TOK*2*4;
  const size_t OFF_XB     = OFF_TOKW  + (size_t)T_TOK*2*4;
  const size_t XB_BYTES   = (size_t)T_TOK*HID*2;                  // 33.55 MB
  const size_t WB       = (size_t)NEXP*FFN_D*HID*2;               // 134.2 MB
  const size_t OFF_W1B  = OFF_XB  + XB_BYTES;
  const size_t OFF_W3B  = OFF_W1B + WB;       // w3b MUST be w1b+WB (WDELTA); part aliases after up
  const size_t OFF_ACTF = OFF_W3B + WB;
  const size_t ACT_BYTES= (size_t)CAP_ROWS*FFN_D*2;               // 136.3 MB
  const size_t WS_FAST  = OFF_ACTF + ACT_BYTES;                   // ~438.8 MB
  const size_t OFF_W2B  = OFF_ACTF + ACT_BYTES;
  const size_t WS_XL    = OFF_W2B + WB;                           // ~573 MB
  if (ws_size < WS_FAST) return;
  const bool xl = (ws_size >= WS_XL);

  char* ws = (char*)d_ws;
  int*   meta    = (int*)ws;
  int*   row_tok = (int*)(ws + OFF_ROWTOK);
  float* row_w   = (float*)(ws + OFF_ROWW);
  int*   tok_top = (int*)(ws + OFF_TOP);
  float* tok_wt  = (float*)(ws + OFF_TOKW);   // pos_of aliases this after scatter
  u16*   xb      = (u16*)(ws + OFF_XB);
  u16*   w1b     = (u16*)(ws + OFF_W1B);
  u16*   w3b     = (u16*)(ws + OFF_W3B);
  u16*   act     = (u16*)(ws + OFF_ACTF);
  u16*   part    = w3b;                        // w3b dead after up
  u16*   w2b     = xl ? (u16*)(ws + OFF_W2B) : w1b;  // separate slot only in XL

  hipMemsetAsync(d_ws, 0, OFF_TOP, stream);   // meta + row_tok + row_w

  // fused front: routing + x->bf16 + w1/w3->bf16 (one launch)
  moe_route  <<<dim3(RT_BLKS + FCVT_BLKS), 256, 0, stream>>>(
      x, gw, meta, tok_top, tok_wt, xb, w1, w1b, w3, w3b);
  moe_prefix <<<1, 1, 0, stream>>>(meta);
  moe_scatter<<<dim3(T_TOK*2/256),    256, 0, stream>>>(tok_top, tok_wt, meta, row_tok, row_w);

  if (xl){
    moe_up_p3<<<dim3(NB_UP2 + CVT_BLKS2), 512, 0, stream>>>(
        xb, w1b, act, meta, row_tok, row_w, w2, w2b);
  } else {
    moe_up_p3<<<dim3(NB_UP2), 512, 0, stream>>>(
        xb, w1b, act, meta, row_tok, row_w, w2, w2b);
    moe_cvt <<<dim3(32768), 256, 0, stream>>>(w2, w1b);   // sequential fallback
  }

  moe_down_f<<<dim3(16*MAX_TILES), 256, 0, stream>>>(act, w2b, part, meta);
  moe_combine<<<dim3(T_TOK), 256, 0, stream>>>(part, (const int*)tok_wt, out);
}

// Round 11
// 1285.237 us; speedup vs baseline: 1.2854x; 1.2854x over previous
//
#include <hip/hip_runtime.h>

// ---------------- problem constants ----------------
#define T_TOK 8192          // B*S tokens
#define HID   2048
#define FFN_D 4096
#define NEXP  8
#define BM    128           // GEMM M tile (both GEMMs)
#define CAP_ROWS (T_TOK*2 + 256)         // 16640
#define MAX_TILES (T_TOK*2/BM + NEXP)    // 136 = 17*8
#define NB_UP   (64*MAX_TILES)           // 8704 GEMM blocks in up launch
#define CVT_BLKS 32768                   // fused w2-cvt blocks in up launch
#define RT_BLKS  2048                    // route blocks in fused front launch
#define FCVT_BLKS 4096                   // w1/w3 cvt tail blocks in front launch

typedef unsigned short u16;
typedef unsigned int   u32;
typedef __attribute__((ext_vector_type(8))) u16    u16x8;
typedef __attribute__((ext_vector_type(8))) __bf16 bf16x8;
typedef __attribute__((ext_vector_type(4))) __bf16 bf16x4;
typedef __attribute__((ext_vector_type(4))) float  f32x4;

// meta[] int layout inside ws
#define M_CNT 0
#define M_CUR 8
#define M_OFF 16
#define M_NT  24
#define M_TEXP 32      // [136]
#define M_TM0  192     // [136]

__device__ __forceinline__ u16 f2bf(float f){   // RNE f32 -> bf16
  u32 u = __float_as_uint(f);
  u += 0x7FFFu + ((u >> 16) & 1u);
  return (u16)(u >> 16);
}
__device__ __forceinline__ float bf2f(u16 v){
  return __uint_as_float(((u32)v) << 16);
}

__device__ __forceinline__ void gload16(const void* g, void* l){
  __builtin_amdgcn_global_load_lds((const __attribute__((address_space(1))) u32*)g,
                                   (__attribute__((address_space(3))) u32*)l, 16, 0, 0);
}

__device__ __forceinline__ bf16x8 cvt8(float4 v0, float4 v1){
  bf16x8 o;
  o[0]=(__bf16)v0.x; o[1]=(__bf16)v0.y; o[2]=(__bf16)v0.z; o[3]=(__bf16)v0.w;
  o[4]=(__bf16)v1.x; o[5]=(__bf16)v1.y; o[6]=(__bf16)v1.z; o[7]=(__bf16)v1.w;
  return o;
}

// ---------------- f32 -> bf16 stream convert (w2 fallback only) ----------------
__global__ __launch_bounds__(256) void moe_cvt(const float* __restrict__ src,
                                               u16* __restrict__ dst){
  size_t i = ((size_t)blockIdx.x * 256 + threadIdx.x) * 8;
  float4 v0 = *(const float4*)(src + i);
  float4 v1 = *(const float4*)(src + i + 4);
  *(bf16x8*)(dst + i) = cvt8(v0, v1);
}

// ---------------- fused front: routing + x->bf16 + w1/w3->bf16 ----------------
// blocks [0, RT_BLKS): one wave per token (4 tokens/block); also writes xb.
// blocks [RT_BLKS, RT_BLKS+FCVT_BLKS): grid-stride convert of w1 and w3.
__global__ __launch_bounds__(256) void moe_route(const float* __restrict__ x,
                                                 const float* __restrict__ gw,
                                                 int* __restrict__ meta,
                                                 int* __restrict__ tok_top,
                                                 float* __restrict__ tok_wt,
                                                 u16* __restrict__ xb,
                                                 const float* __restrict__ w1,
                                                 u16* __restrict__ w1b,
                                                 const float* __restrict__ w3,
                                                 u16* __restrict__ w3b){
  if (blockIdx.x >= RT_BLKS){
    const size_t NELEM = (size_t)NEXP * FFN_D * HID;            // 67,108,864 per weight
    const size_t STR   = (size_t)FCVT_BLKS * 256 * 8;           // 8,388,608
    size_t i = ((size_t)(blockIdx.x - RT_BLKS) * 256 + threadIdx.x) * 8;
    for (; i < NELEM; i += STR){
      float4 a0 = *(const float4*)(w1 + i);
      float4 a1 = *(const float4*)(w1 + i + 4);
      *(bf16x8*)(w1b + i) = cvt8(a0, a1);
      float4 b0 = *(const float4*)(w3 + i);
      float4 b1 = *(const float4*)(w3 + i + 4);
      *(bf16x8*)(w3b + i) = cvt8(b0, b1);
    }
    return;
  }

  const int wid  = threadIdx.x >> 6;
  const int lane = threadIdx.x & 63;
  const int tok  = blockIdx.x * 4 + wid;
  const float* xr = x  + (size_t)tok * HID;
  u16*         xw = xb + (size_t)tok * HID;

  float s[NEXP];
  #pragma unroll
  for (int e=0;e<NEXP;e++) s[e]=0.f;

  for (int k = lane*4; k < HID; k += 256){
    const float4 xv = *(const float4*)(xr + k);
    bf16x4 xo;
    xo[0]=(__bf16)xv.x; xo[1]=(__bf16)xv.y; xo[2]=(__bf16)xv.z; xo[3]=(__bf16)xv.w;
    *(bf16x4*)(xw + k) = xo;
    #pragma unroll
    for (int e=0;e<NEXP;e++){
      const float4 g = *(const float4*)(gw + e*HID + k);
      s[e] += xv.x*g.x + xv.y*g.y + xv.z*g.z + xv.w*g.w;
    }
  }
  #pragma unroll
  for (int o=32;o;o>>=1){
    #pragma unroll
    for (int e=0;e<NEXP;e++) s[e] += __shfl_xor(s[e], o);
  }
  if (lane==0){
    float m1 = s[0]; int a = 0;
    #pragma unroll
    for (int e=1;e<NEXP;e++) if (s[e] > m1){ m1 = s[e]; a = e; }
    float m2 = -3.0e38f; int b = 0;
    #pragma unroll
    for (int e=0;e<NEXP;e++) if (e != a && s[e] > m2){ m2 = s[e]; b = e; }
    const float r  = __expf(m2 - m1);
    const float wa = 1.f / (1.f + r);
    tok_top[tok*2]   = a;  tok_top[tok*2+1] = b;
    tok_wt[tok*2]    = wa; tok_wt[tok*2+1]  = r * wa;
    atomicAdd(&meta[M_CNT + a], 1);
    atomicAdd(&meta[M_CNT + b], 1);
  }
}

// ---------------- prefix + tile table ----------------
__global__ void moe_prefix(int* __restrict__ meta){
  if (threadIdx.x != 0 || blockIdx.x != 0) return;
  int off = 0, nt = 0;
  for (int e=0;e<NEXP;e++){
    const int c = meta[M_CNT + e];
    meta[M_OFF + e] = off;
    meta[M_CUR + e] = off;
    const int ntE = (c + BM - 1) / BM;
    for (int i=0;i<ntE;i++){ meta[M_TEXP + nt] = e; meta[M_TM0 + nt] = off + i*BM; nt++; }
    off += c;
  }
  meta[M_NT] = nt;
}

// ---------------- scatter (records pos_of aliased on tok_wt) ----------------
__global__ __launch_bounds__(256) void moe_scatter(const int* __restrict__ tok_top,
                                                   float* __restrict__ tok_wt,
                                                   int* __restrict__ meta,
                                                   int* __restrict__ row_tok,
                                                   float* __restrict__ row_w){
  const int i = blockIdx.x * 256 + threadIdx.x;
  const int e = tok_top[i];
  const float w = tok_wt[i];
  const int pos = atomicAdd(&meta[M_CUR + e], 1);
  row_tok[pos] = i >> 1;
  row_w[pos]   = w;
  ((int*)tok_wt)[i] = pos;
}

// ================= up-GEMM (proven structure) + XCD swizzle + fused w2 cvt =================
// 1-D grid. GEMM blocks b < NB_UP: tile=(b>>3)>>3, n=(b&7)+8*((b>>3)&7).
// XCD k owns N-columns n===k (mod 8): its 8 B-panels (4 MB) stay L2-resident across M-tiles.
// LDS: [rows][64] bf16 in 16B chunks; logical chunk c of row r at pc = c ^ (r&7).
__global__ __launch_bounds__(256,2) void moe_up_f(
    const u16* __restrict__ xb, const u16* __restrict__ w1b, const u16* __restrict__ w3b,
    u16* __restrict__ act, const int* __restrict__ meta,
    const int* __restrict__ row_tok, const float* __restrict__ row_w,
    const float* __restrict__ w2, u16* __restrict__ w2b){
  if (blockIdx.x >= NB_UP){
    const size_t base = ((size_t)(blockIdx.x - NB_UP)) * 2048 + (size_t)threadIdx.x * 8;
    float4 v0 = *(const float4*)(w2 + base);
    float4 v1 = *(const float4*)(w2 + base + 4);
    *(bf16x8*)(w2b + base) = cvt8(v0, v1);
    return;
  }
  const int b    = blockIdx.x;
  const int q    = b >> 3;
  const int tile = q >> 3;                 // 0..135
  const int n0   = ((b & 7) + 8*(q & 7)) * 64;
  if (tile >= meta[M_NT]) return;
  const int e      = meta[M_TEXP + tile];
  const int m0     = meta[M_TM0 + tile];
  const int rowEnd = meta[M_OFF + e] + meta[M_CNT + e];

  __shared__ u16 As[128*64];     // 16 KB
  __shared__ u16 Bs[2*64*64];    // 16 KB (w1 | w3)

  const int t    = threadIdx.x;
  const int lane = t & 63;
  const int wid  = t >> 6;
  const int wm   = wid >> 1, wn = wid & 1;
  const int lr = lane & 15;
  const int lq = lane >> 4;

  u32 aoff[4], boff[4];
  #pragma unroll
  for (int i=0;i<4;i++){
    const int g  = i*256 + t;        // chunk id 0..1023
    const int r  = g >> 3;           // 0..127
    const int pc = g & 7;
    aoff[i] = (u32)row_tok[m0 + r] * HID + (u32)((pc ^ (r & 7)) * 8);
    const int rr = r & 63;
    boff[i] = (u32)(n0 + rr) * HID + (u32)((pc ^ (rr & 7)) * 8);
  }
  const size_t eW = (size_t)e * FFN_D * HID;
  const u16* w1e = w1b + eW;
  const u16* w3e = w3b + eW;

  f32x4 accG[4][2], accU[4][2];
  #pragma unroll
  for (int i=0;i<4;i++){
    #pragma unroll
    for (int j=0;j<2;j++){ accG[i][j]=(f32x4)0.f; accU[i][j]=(f32x4)0.f; }
  }

  for (int kk = 0; kk < HID; kk += 64){
    __syncthreads();
    #pragma unroll
    for (int i=0;i<4;i++)
      gload16(xb + aoff[i] + kk, As + (size_t)(i*256 + wid*64)*8);
    gload16(w1e + boff[0] + kk, Bs + (size_t)(0*256 + wid*64)*8);
    gload16(w1e + boff[1] + kk, Bs + (size_t)(1*256 + wid*64)*8);
    gload16(w3e + boff[2] + kk, Bs + (size_t)(2*256 + wid*64)*8);
    gload16(w3e + boff[3] + kk, Bs + (size_t)(3*256 + wid*64)*8);
    __syncthreads();

    #pragma unroll
    for (int ks=0; ks<2; ks++){
      const int c = ks*4 + lq;
      bf16x8 a[4], bG[2], bU[2];
      #pragma unroll
      for (int mi=0;mi<4;mi++){
        const int r = wm*64 + mi*16 + lr;
        a[mi] = *(const bf16x8*)(As + r*64 + (c ^ (r&7))*8);
      }
      #pragma unroll
      for (int ni=0;ni<2;ni++){
        const int r  = wn*32 + ni*16 + lr;
        const int po = (c ^ (r&7))*8;
        bG[ni] = *(const bf16x8*)(Bs + r*64 + po);
        bU[ni] = *(const bf16x8*)(Bs + 4096 + r*64 + po);
      }
      #pragma unroll
      for (int mi=0;mi<4;mi++){
        #pragma unroll
        for (int ni=0;ni<2;ni++){
          accG[mi][ni] = __builtin_amdgcn_mfma_f32_16x16x32_bf16(a[mi], bG[ni], accG[mi][ni],0,0,0);
          accU[mi][ni] = __builtin_amdgcn_mfma_f32_16x16x32_bf16(a[mi], bU[ni], accU[mi][ni],0,0,0);
        }
      }
    }
  }

  const int l4 = lq * 4;
  #pragma unroll
  for (int mi=0;mi<4;mi++){
    #pragma unroll
    for (int r=0;r<4;r++){
      const int pos = m0 + wm*64 + mi*16 + l4 + r;
      if (pos < rowEnd){
        const float rw = row_w[pos];
        #pragma unroll
        for (int ni=0;ni<2;ni++){
          const int n = n0 + wn*32 + ni*16 + lr;
          const float g = accG[mi][ni][r];
          const float u = accU[mi][ni][r];
          act[(size_t)pos * FFN_D + n] = f2bf(fmaxf(g, 0.f) * u * rw);
        }
      }
    }
  }
}

// ================= down-GEMM (proven 128x128) + XCD swizzle, no atomics =================
// 1-D grid of 16*136=2176. Decode: tile=(b>>3)>>1, n=((b&7)+8*((b>>3)&1))*128.
// XCD k owns N-columns {k, k+8}, paired per M-tile: B working set 2 MB (L2-resident),
// A-panel's two uses are back-to-back (second is an L2 hit).
__global__ __launch_bounds__(256,2) void moe_down_f(
    const u16* __restrict__ act, const u16* __restrict__ w2b,
    u16* __restrict__ part, const int* __restrict__ meta){
  const int b    = blockIdx.x;
  const int q    = b >> 3;
  const int tile = q >> 1;
  const int n0   = ((b & 7) + 8*(q & 1)) * 128;
  if (tile >= meta[M_NT]) return;
  const int e      = meta[M_TEXP + tile];
  const int m0     = meta[M_TM0 + tile];
  const int rowEnd = meta[M_OFF + e] + meta[M_CNT + e];

  __shared__ u16 As[128*64];   // 16 KB
  __shared__ u16 Bs[128*64];   // 16 KB

  const int t    = threadIdx.x;
  const int lane = t & 63;
  const int wid  = t >> 6;
  const int wm   = wid >> 1, wn = wid & 1;
  const int lr = lane & 15;
  const int lq = lane >> 4;

  u32 aoff[4], boff[4];
  const u16* w2e = w2b + (size_t)e * HID * FFN_D;
  #pragma unroll
  for (int i=0;i<4;i++){
    const int g  = i*256 + t;
    const int r  = g >> 3;           // 0..127
    const int pc = g & 7;
    const int c8 = (pc ^ (r & 7)) * 8;
    aoff[i] = (u32)(m0 + r) * FFN_D + (u32)c8;
    boff[i] = (u32)(n0 + r) * FFN_D + (u32)c8;
  }

  f32x4 acc[4][4];
  #pragma unroll
  for (int i=0;i<4;i++){
    #pragma unroll
    for (int j=0;j<4;j++) acc[i][j]=(f32x4)0.f;
  }

  for (int kk = 0; kk < FFN_D; kk += 64){
    __syncthreads();
    #pragma unroll
    for (int i=0;i<4;i++)
      gload16(act + aoff[i] + kk, As + (size_t)(i*256 + wid*64)*8);
    #pragma unroll
    for (int i=0;i<4;i++)
      gload16(w2e + boff[i] + kk, Bs + (size_t)(i*256 + wid*64)*8);
    __syncthreads();

    #pragma unroll
    for (int ks=0; ks<2; ks++){
      const int c = ks*4 + lq;
      bf16x8 a[4], bb[4];
      #pragma unroll
      for (int mi=0;mi<4;mi++){
        const int r = wm*64 + mi*16 + lr;
        a[mi] = *(const bf16x8*)(As + r*64 + (c ^ (r&7))*8);
      }
      #pragma unroll
      for (int ni=0;ni<4;ni++){
        const int r = wn*64 + ni*16 + lr;
        bb[ni] = *(const bf16x8*)(Bs + r*64 + (c ^ (r&7))*8);
      }
      #pragma unroll
      for (int mi=0;mi<4;mi++){
        #pragma unroll
        for (int ni=0;ni<4;ni++)
          acc[mi][ni] = __builtin_amdgcn_mfma_f32_16x16x32_bf16(a[mi], bb[ni], acc[mi][ni],0,0,0);
      }
    }
  }

  const int l4 = lq * 4;
  #pragma unroll
  for (int mi=0;mi<4;mi++){
    #pragma unroll
    for (int r=0;r<4;r++){
      const int pos = m0 + wm*64 + mi*16 + l4 + r;
      if (pos < rowEnd){
        u16* prow = part + (size_t)pos * HID;
        #pragma unroll
        for (int ni=0;ni<4;ni++){
          const int n = n0 + wn*64 + ni*16 + lr;
          prow[n] = f2bf(acc[mi][ni][r]);
        }
      }
    }
  }
}

// ---------------- combine: out[tok] = part[p0] + part[p1] ----------------
__global__ __launch_bounds__(256) void moe_combine(const u16* __restrict__ part,
                                                   const int* __restrict__ pos_of,
                                                   float* __restrict__ out){
  const int tok = blockIdx.x;
  const int p0 = pos_of[tok*2];
  const int p1 = pos_of[tok*2+1];
  const int h = threadIdx.x * 8;
  const u16x8 a = *(const u16x8*)(part + (size_t)p0 * HID + h);
  const u16x8 b = *(const u16x8*)(part + (size_t)p1 * HID + h);
  float4 o0, o1;
  o0.x = bf2f(a[0]) + bf2f(b[0]);
  o0.y = bf2f(a[1]) + bf2f(b[1]);
  o0.z = bf2f(a[2]) + bf2f(b[2]);
  o0.w = bf2f(a[3]) + bf2f(b[3]);
  o1.x = bf2f(a[4]) + bf2f(b[4]);
  o1.y = bf2f(a[5]) + bf2f(b[5]);
  o1.z = bf2f(a[6]) + bf2f(b[6]);
  o1.w = bf2f(a[7]) + bf2f(b[7]);
  float* orow = out + (size_t)tok * HID + h;
  *(float4*)orow = o0;
  *(float4*)(orow + 4) = o1;
}

// ---------------- host ----------------
extern "C" void kernel_launch(void* const* d_in, const int* in_sizes, int n_in,
                              void* d_out, int out_size, void* d_ws, size_t ws_size,
                              hipStream_t stream) {
  const float* x  = (const float*)d_in[0];
  const float* gw = (const float*)d_in[1];
  const float* w1 = (const float*)d_in[2];
  const float* w2 = (const float*)d_in[3];
  const float* w3 = (const float*)d_in[4];
  float* out = (float*)d_out;

  const size_t OFF_ROWTOK = 4096;
  const size_t OFF_ROWW   = OFF_ROWTOK + (size_t)CAP_ROWS*4;
  const size_t OFF_TOP    = OFF_ROWW  + (size_t)CAP_ROWS*4;
  const size_t OFF_TOKW   = OFF_TOP   + (size_t)T_TOK*2*4;
  const size_t OFF_XB     = OFF_TOKW  + (size_t)T_TOK*2*4;
  const size_t XB_BYTES   = (size_t)T_TOK*HID*2;                  // 33.55 MB
  const size_t WB       = (size_t)NEXP*FFN_D*HID*2;               // 134.2 MB
  const size_t OFF_W1B  = OFF_XB  + XB_BYTES;
  const size_t OFF_W3B  = OFF_W1B + WB;       // part aliases this after up
  const size_t OFF_ACTF = OFF_W3B + WB;
  const size_t ACT_BYTES= (size_t)CAP_ROWS*FFN_D*2;               // 136.3 MB
  const size_t WS_FAST  = OFF_ACTF + ACT_BYTES;                   // ~438.8 MB
  const size_t OFF_W2B  = OFF_ACTF + ACT_BYTES;
  const size_t WS_XL    = OFF_W2B + WB;                           // ~573 MB
  if (ws_size < WS_FAST) return;
  const bool xl = (ws_size >= WS_XL);

  char* ws = (char*)d_ws;
  int*   meta    = (int*)ws;
  int*   row_tok = (int*)(ws + OFF_ROWTOK);
  float* row_w   = (float*)(ws + OFF_ROWW);
  int*   tok_top = (int*)(ws + OFF_TOP);
  float* tok_wt  = (float*)(ws + OFF_TOKW);   // pos_of aliases this after scatter
  u16*   xb      = (u16*)(ws + OFF_XB);
  u16*   w1b     = (u16*)(ws + OFF_W1B);
  u16*   w3b     = (u16*)(ws + OFF_W3B);
  u16*   act     = (u16*)(ws + OFF_ACTF);
  u16*   part    = w3b;                        // w3b dead after up
  u16*   w2b     = xl ? (u16*)(ws + OFF_W2B) : w1b;  // separate slot only in XL

  hipMemsetAsync(d_ws, 0, OFF_TOP, stream);   // meta + row_tok + row_w

  // fused front: routing + x->bf16 + w1/w3->bf16 (one launch)
  moe_route  <<<dim3(RT_BLKS + FCVT_BLKS), 256, 0, stream>>>(
      x, gw, meta, tok_top, tok_wt, xb, w1, w1b, w3, w3b);
  moe_prefix <<<1, 1, 0, stream>>>(meta);
  moe_scatter<<<dim3(T_TOK*2/256),    256, 0, stream>>>(tok_top, tok_wt, meta, row_tok, row_w);

  if (xl){
    // w2 cvt rides inside the up launch (tail blocks past NB_UP)
    moe_up_f<<<dim3(NB_UP + CVT_BLKS), 256, 0, stream>>>(
        xb, w1b, w3b, act, meta, row_tok, row_w, w2, w2b);
  } else {
    moe_up_f<<<dim3(NB_UP), 256, 0, stream>>>(
        xb, w1b, w3b, act, meta, row_tok, row_w, w2, w2b);
    moe_cvt <<<dim3(32768), 256, 0, stream>>>(w2, w1b);   // sequential fallback
  }

  moe_down_f<<<dim3(16*MAX_TILES), 256, 0, stream>>>(act, w2b, part, meta);
  moe_combine<<<dim3(T_TOK), 256, 0, stream>>>(part, (const int*)tok_wt, out);
}

// Round 12
// 1271.849 us; speedup vs baseline: 1.2989x; 1.0105x over previous
//
#include <hip/hip_runtime.h>

// ---------------- problem constants ----------------
#define T_TOK 8192          // B*S tokens
#define HID   2048
#define FFN_D 4096
#define NEXP  8
#define BM    128           // GEMM M tile (both GEMMs)
#define CAP_ROWS (T_TOK*2 + 256)         // 16640
#define MAX_TILES (T_TOK*2/BM + NEXP)    // 136 = 17*8
#define NB_UP   (64*MAX_TILES)           // 8704 GEMM blocks in up launch
#define CVT_BLKS 32768                   // fused w2-cvt blocks in up launch
#define RT_BLKS  2048                    // route blocks in fused front launch
#define FCVT_BLKS 10240                  // w1/w3 cvt tail blocks in front launch
#define NB_DN   (32*MAX_TILES)           // 4352 down blocks (16 N x 2 Kz per tile)
#define PROWS   16384                    // rows per part plane (pos < 16384 always)

typedef unsigned short u16;
typedef unsigned int   u32;
typedef __attribute__((ext_vector_type(8))) u16    u16x8;
typedef __attribute__((ext_vector_type(8))) __bf16 bf16x8;
typedef __attribute__((ext_vector_type(4))) __bf16 bf16x4;
typedef __attribute__((ext_vector_type(4))) float  f32x4;

// meta[] int layout inside ws
#define M_CNT 0
#define M_CUR 8
#define M_OFF 16
#define M_NT  24
#define M_TEXP 32      // [136]
#define M_TM0  192     // [136]

__device__ __forceinline__ u16 f2bf(float f){   // RNE f32 -> bf16
  u32 u = __float_as_uint(f);
  u += 0x7FFFu + ((u >> 16) & 1u);
  return (u16)(u >> 16);
}
__device__ __forceinline__ float bf2f(u16 v){
  return __uint_as_float(((u32)v) << 16);
}

__device__ __forceinline__ void gload16(const void* g, void* l){
  __builtin_amdgcn_global_load_lds((const __attribute__((address_space(1))) u32*)g,
                                   (__attribute__((address_space(3))) u32*)l, 16, 0, 0);
}

__device__ __forceinline__ bf16x8 cvt8(float4 v0, float4 v1){
  bf16x8 o;
  o[0]=(__bf16)v0.x; o[1]=(__bf16)v0.y; o[2]=(__bf16)v0.z; o[3]=(__bf16)v0.w;
  o[4]=(__bf16)v1.x; o[5]=(__bf16)v1.y; o[6]=(__bf16)v1.z; o[7]=(__bf16)v1.w;
  return o;
}

// ---------------- f32 -> bf16 stream convert (w2 fallback only) ----------------
__global__ __launch_bounds__(256) void moe_cvt(const float* __restrict__ src,
                                               u16* __restrict__ dst){
  size_t i = ((size_t)blockIdx.x * 256 + threadIdx.x) * 8;
  float4 v0 = *(const float4*)(src + i);
  float4 v1 = *(const float4*)(src + i + 4);
  *(bf16x8*)(dst + i) = cvt8(v0, v1);
}

// ---------------- fused front: routing + x->bf16 + w1/w3->bf16 ----------------
// blocks [0, RT_BLKS): one wave per token (4 tokens/block); also writes xb.
// blocks [RT_BLKS, RT_BLKS+FCVT_BLKS): grid-stride convert of w1 and w3.
__global__ __launch_bounds__(256) void moe_route(const float* __restrict__ x,
                                                 const float* __restrict__ gw,
                                                 int* __restrict__ meta,
                                                 int* __restrict__ tok_top,
                                                 float* __restrict__ tok_wt,
                                                 u16* __restrict__ xb,
                                                 const float* __restrict__ w1,
                                                 u16* __restrict__ w1b,
                                                 const float* __restrict__ w3,
                                                 u16* __restrict__ w3b){
  if (blockIdx.x >= RT_BLKS){
    const size_t NELEM = (size_t)NEXP * FFN_D * HID;            // 67,108,864 per weight
    const size_t STR   = (size_t)FCVT_BLKS * 256 * 8;           // 20,971,520
    size_t i = ((size_t)(blockIdx.x - RT_BLKS) * 256 + threadIdx.x) * 8;
    for (; i < NELEM; i += STR){
      float4 a0 = *(const float4*)(w1 + i);
      float4 a1 = *(const float4*)(w1 + i + 4);
      *(bf16x8*)(w1b + i) = cvt8(a0, a1);
      float4 b0 = *(const float4*)(w3 + i);
      float4 b1 = *(const float4*)(w3 + i + 4);
      *(bf16x8*)(w3b + i) = cvt8(b0, b1);
    }
    return;
  }

  const int wid  = threadIdx.x >> 6;
  const int lane = threadIdx.x & 63;
  const int tok  = blockIdx.x * 4 + wid;
  const float* xr = x  + (size_t)tok * HID;
  u16*         xw = xb + (size_t)tok * HID;

  float s[NEXP];
  #pragma unroll
  for (int e=0;e<NEXP;e++) s[e]=0.f;

  for (int k = lane*4; k < HID; k += 256){
    const float4 xv = *(const float4*)(xr + k);
    bf16x4 xo;
    xo[0]=(__bf16)xv.x; xo[1]=(__bf16)xv.y; xo[2]=(__bf16)xv.z; xo[3]=(__bf16)xv.w;
    *(bf16x4*)(xw + k) = xo;
    #pragma unroll
    for (int e=0;e<NEXP;e++){
      const float4 g = *(const float4*)(gw + e*HID + k);
      s[e] += xv.x*g.x + xv.y*g.y + xv.z*g.z + xv.w*g.w;
    }
  }
  #pragma unroll
  for (int o=32;o;o>>=1){
    #pragma unroll
    for (int e=0;e<NEXP;e++) s[e] += __shfl_xor(s[e], o);
  }
  if (lane==0){
    float m1 = s[0]; int a = 0;
    #pragma unroll
    for (int e=1;e<NEXP;e++) if (s[e] > m1){ m1 = s[e]; a = e; }
    float m2 = -3.0e38f; int b = 0;
    #pragma unroll
    for (int e=0;e<NEXP;e++) if (e != a && s[e] > m2){ m2 = s[e]; b = e; }
    const float r  = __expf(m2 - m1);
    const float wa = 1.f / (1.f + r);
    tok_top[tok*2]   = a;  tok_top[tok*2+1] = b;
    tok_wt[tok*2]    = wa; tok_wt[tok*2+1]  = r * wa;
    atomicAdd(&meta[M_CNT + a], 1);
    atomicAdd(&meta[M_CNT + b], 1);
  }
}

// ---------------- prefix + tile table ----------------
__global__ void moe_prefix(int* __restrict__ meta){
  if (threadIdx.x != 0 || blockIdx.x != 0) return;
  int off = 0, nt = 0;
  for (int e=0;e<NEXP;e++){
    const int c = meta[M_CNT + e];
    meta[M_OFF + e] = off;
    meta[M_CUR + e] = off;
    const int ntE = (c + BM - 1) / BM;
    for (int i=0;i<ntE;i++){ meta[M_TEXP + nt] = e; meta[M_TM0 + nt] = off + i*BM; nt++; }
    off += c;
  }
  meta[M_NT] = nt;
}

// ---------------- scatter (records pos_of aliased on tok_wt) ----------------
__global__ __launch_bounds__(256) void moe_scatter(const int* __restrict__ tok_top,
                                                   float* __restrict__ tok_wt,
                                                   int* __restrict__ meta,
                                                   int* __restrict__ row_tok,
                                                   float* __restrict__ row_w){
  const int i = blockIdx.x * 256 + threadIdx.x;
  const int e = tok_top[i];
  const float w = tok_wt[i];
  const int pos = atomicAdd(&meta[M_CUR + e], 1);
  row_tok[pos] = i >> 1;
  row_w[pos]   = w;
  ((int*)tok_wt)[i] = pos;
}

// ================= up-GEMM (proven structure) + XCD swizzle + fused w2 cvt =================
// 1-D grid. GEMM blocks b < NB_UP: tile=(b>>3)>>3, n=(b&7)+8*((b>>3)&7).
// XCD k owns N-columns n===k (mod 8): its 8 B-panels (4 MB) stay L2-resident across M-tiles.
// LDS: [rows][64] bf16 in 16B chunks; logical chunk c of row r at pc = c ^ (r&7).
__global__ __launch_bounds__(256,2) void moe_up_f(
    const u16* __restrict__ xb, const u16* __restrict__ w1b, const u16* __restrict__ w3b,
    u16* __restrict__ act, const int* __restrict__ meta,
    const int* __restrict__ row_tok, const float* __restrict__ row_w,
    const float* __restrict__ w2, u16* __restrict__ w2b){
  if (blockIdx.x >= NB_UP){
    const size_t base = ((size_t)(blockIdx.x - NB_UP)) * 2048 + (size_t)threadIdx.x * 8;
    float4 v0 = *(const float4*)(w2 + base);
    float4 v1 = *(const float4*)(w2 + base + 4);
    *(bf16x8*)(w2b + base) = cvt8(v0, v1);
    return;
  }
  const int b    = blockIdx.x;
  const int q    = b >> 3;
  const int tile = q >> 3;                 // 0..135
  const int n0   = ((b & 7) + 8*(q & 7)) * 64;
  if (tile >= meta[M_NT]) return;
  const int e      = meta[M_TEXP + tile];
  const int m0     = meta[M_TM0 + tile];
  const int rowEnd = meta[M_OFF + e] + meta[M_CNT + e];

  __shared__ u16 As[128*64];     // 16 KB
  __shared__ u16 Bs[2*64*64];    // 16 KB (w1 | w3)

  const int t    = threadIdx.x;
  const int lane = t & 63;
  const int wid  = t >> 6;
  const int wm   = wid >> 1, wn = wid & 1;
  const int lr = lane & 15;
  const int lq = lane >> 4;

  u32 aoff[4], boff[4];
  #pragma unroll
  for (int i=0;i<4;i++){
    const int g  = i*256 + t;        // chunk id 0..1023
    const int r  = g >> 3;           // 0..127
    const int pc = g & 7;
    aoff[i] = (u32)row_tok[m0 + r] * HID + (u32)((pc ^ (r & 7)) * 8);
    const int rr = r & 63;
    boff[i] = (u32)(n0 + rr) * HID + (u32)((pc ^ (rr & 7)) * 8);
  }
  const size_t eW = (size_t)e * FFN_D * HID;
  const u16* w1e = w1b + eW;
  const u16* w3e = w3b + eW;

  f32x4 accG[4][2], accU[4][2];
  #pragma unroll
  for (int i=0;i<4;i++){
    #pragma unroll
    for (int j=0;j<2;j++){ accG[i][j]=(f32x4)0.f; accU[i][j]=(f32x4)0.f; }
  }

  for (int kk = 0; kk < HID; kk += 64){
    __syncthreads();
    #pragma unroll
    for (int i=0;i<4;i++)
      gload16(xb + aoff[i] + kk, As + (size_t)(i*256 + wid*64)*8);
    gload16(w1e + boff[0] + kk, Bs + (size_t)(0*256 + wid*64)*8);
    gload16(w1e + boff[1] + kk, Bs + (size_t)(1*256 + wid*64)*8);
    gload16(w3e + boff[2] + kk, Bs + (size_t)(2*256 + wid*64)*8);
    gload16(w3e + boff[3] + kk, Bs + (size_t)(3*256 + wid*64)*8);
    __syncthreads();

    #pragma unroll
    for (int ks=0; ks<2; ks++){
      const int c = ks*4 + lq;
      bf16x8 a[4], bG[2], bU[2];
      #pragma unroll
      for (int mi=0;mi<4;mi++){
        const int r = wm*64 + mi*16 + lr;
        a[mi] = *(const bf16x8*)(As + r*64 + (c ^ (r&7))*8);
      }
      #pragma unroll
      for (int ni=0;ni<2;ni++){
        const int r  = wn*32 + ni*16 + lr;
        const int po = (c ^ (r&7))*8;
        bG[ni] = *(const bf16x8*)(Bs + r*64 + po);
        bU[ni] = *(const bf16x8*)(Bs + 4096 + r*64 + po);
      }
      #pragma unroll
      for (int mi=0;mi<4;mi++){
        #pragma unroll
        for (int ni=0;ni<2;ni++){
          accG[mi][ni] = __builtin_amdgcn_mfma_f32_16x16x32_bf16(a[mi], bG[ni], accG[mi][ni],0,0,0);
          accU[mi][ni] = __builtin_amdgcn_mfma_f32_16x16x32_bf16(a[mi], bU[ni], accU[mi][ni],0,0,0);
        }
      }
    }
  }

  const int l4 = lq * 4;
  #pragma unroll
  for (int mi=0;mi<4;mi++){
    #pragma unroll
    for (int r=0;r<4;r++){
      const int pos = m0 + wm*64 + mi*16 + l4 + r;
      if (pos < rowEnd){
        const float rw = row_w[pos];
        #pragma unroll
        for (int ni=0;ni<2;ni++){
          const int n = n0 + wn*32 + ni*16 + lr;
          const float g = accG[mi][ni][r];
          const float u = accU[mi][ni][r];
          act[(size_t)pos * FFN_D + n] = f2bf(fmaxf(g, 0.f) * u * rw);
        }
      }
    }
  }
}

// ================= down-GEMM (proven 128x128) + XCD swizzle + K-split x2 =================
// 1-D grid of 32*136=4352. Decode: r=b&7 (XCD), q=b>>3: h=q&1 (N-half), kz=(q>>1)&1
// (K-half), tile=q>>2. Per tile, XCD k runs its 4 (h,kz) blocks back-to-back:
// act halves fetched once each per XCD; B (cols {k,k+8}) stays L2-resident.
// Each block computes K in [kz*2048, kz*2048+2048) and writes bf16 partials to
// part[kz][pos][:]. K-split doubles block count -> fixes the 2.4-round dispatch
// tail that held down at ~714 TF.
__global__ __launch_bounds__(256,2) void moe_down_f(
    const u16* __restrict__ act, const u16* __restrict__ w2b,
    u16* __restrict__ part, const int* __restrict__ meta){
  const int b    = blockIdx.x;
  const int q    = b >> 3;
  const int h    = q & 1;
  const int kz   = (q >> 1) & 1;
  const int tile = q >> 2;
  const int n0   = ((b & 7) + 8*h) * 128;
  if (tile >= meta[M_NT]) return;
  const int e      = meta[M_TEXP + tile];
  const int m0     = meta[M_TM0 + tile];
  const int rowEnd = meta[M_OFF + e] + meta[M_CNT + e];

  __shared__ u16 As[128*64];   // 16 KB
  __shared__ u16 Bs[128*64];   // 16 KB

  const int t    = threadIdx.x;
  const int lane = t & 63;
  const int wid  = t >> 6;
  const int wm   = wid >> 1, wn = wid & 1;
  const int lr = lane & 15;
  const int lq = lane >> 4;

  u32 aoff[4], boff[4];
  const u16* w2e = w2b + (size_t)e * HID * FFN_D;
  #pragma unroll
  for (int i=0;i<4;i++){
    const int g  = i*256 + t;
    const int r  = g >> 3;           // 0..127
    const int pc = g & 7;
    const int c8 = (pc ^ (r & 7)) * 8;
    aoff[i] = (u32)(m0 + r) * FFN_D + (u32)c8;
    boff[i] = (u32)(n0 + r) * FFN_D + (u32)c8;
  }

  f32x4 acc[4][4];
  #pragma unroll
  for (int i=0;i<4;i++){
    #pragma unroll
    for (int j=0;j<4;j++) acc[i][j]=(f32x4)0.f;
  }

  const int k0 = kz * (FFN_D/2);
  for (int kk = k0; kk < k0 + FFN_D/2; kk += 64){
    __syncthreads();
    #pragma unroll
    for (int i=0;i<4;i++)
      gload16(act + aoff[i] + kk, As + (size_t)(i*256 + wid*64)*8);
    #pragma unroll
    for (int i=0;i<4;i++)
      gload16(w2e + boff[i] + kk, Bs + (size_t)(i*256 + wid*64)*8);
    __syncthreads();

    #pragma unroll
    for (int ks=0; ks<2; ks++){
      const int c = ks*4 + lq;
      bf16x8 a[4], bb[4];
      #pragma unroll
      for (int mi=0;mi<4;mi++){
        const int r = wm*64 + mi*16 + lr;
        a[mi] = *(const bf16x8*)(As + r*64 + (c ^ (r&7))*8);
      }
      #pragma unroll
      for (int ni=0;ni<4;ni++){
        const int r = wn*64 + ni*16 + lr;
        bb[ni] = *(const bf16x8*)(Bs + r*64 + (c ^ (r&7))*8);
      }
      #pragma unroll
      for (int mi=0;mi<4;mi++){
        #pragma unroll
        for (int ni=0;ni<4;ni++)
          acc[mi][ni] = __builtin_amdgcn_mfma_f32_16x16x32_bf16(a[mi], bb[ni], acc[mi][ni],0,0,0);
      }
    }
  }

  const int l4 = lq * 4;
  u16* pbase = part + (size_t)kz * PROWS * HID;
  #pragma unroll
  for (int mi=0;mi<4;mi++){
    #pragma unroll
    for (int r=0;r<4;r++){
      const int pos = m0 + wm*64 + mi*16 + l4 + r;
      if (pos < rowEnd){
        u16* prow = pbase + (size_t)pos * HID;
        #pragma unroll
        for (int ni=0;ni<4;ni++){
          const int n = n0 + wn*64 + ni*16 + lr;
          prow[n] = f2bf(acc[mi][ni][r]);
        }
      }
    }
  }
}

// ---------------- combine: out[tok] = sum of 4 bf16 partials (2 pos x 2 K-halves) ----------------
__global__ __launch_bounds__(256) void moe_combine(const u16* __restrict__ part,
                                                   const int* __restrict__ pos_of,
                                                   float* __restrict__ out){
  const int tok = blockIdx.x;
  const int p0 = pos_of[tok*2];
  const int p1 = pos_of[tok*2+1];
  const int h = threadIdx.x * 8;
  const u16x8 a0 = *(const u16x8*)(part + ((size_t)p0)            * HID + h);
  const u16x8 a1 = *(const u16x8*)(part + ((size_t)PROWS + p0)    * HID + h);
  const u16x8 b0 = *(const u16x8*)(part + ((size_t)p1)            * HID + h);
  const u16x8 b1 = *(const u16x8*)(part + ((size_t)PROWS + p1)    * HID + h);
  float4 o0, o1;
  o0.x = (bf2f(a0[0])+bf2f(a1[0])) + (bf2f(b0[0])+bf2f(b1[0]));
  o0.y = (bf2f(a0[1])+bf2f(a1[1])) + (bf2f(b0[1])+bf2f(b1[1]));
  o0.z = (bf2f(a0[2])+bf2f(a1[2])) + (bf2f(b0[2])+bf2f(b1[2]));
  o0.w = (bf2f(a0[3])+bf2f(a1[3])) + (bf2f(b0[3])+bf2f(b1[3]));
  o1.x = (bf2f(a0[4])+bf2f(a1[4])) + (bf2f(b0[4])+bf2f(b1[4]));
  o1.y = (bf2f(a0[5])+bf2f(a1[5])) + (bf2f(b0[5])+bf2f(b1[5]));
  o1.z = (bf2f(a0[6])+bf2f(a1[6])) + (bf2f(b0[6])+bf2f(b1[6]));
  o1.w = (bf2f(a0[7])+bf2f(a1[7])) + (bf2f(b0[7])+bf2f(b1[7]));
  float* orow = out + (size_t)tok * HID + h;
  *(float4*)orow = o0;
  *(float4*)(orow + 4) = o1;
}

// ---------------- host ----------------
extern "C" void kernel_launch(void* const* d_in, const int* in_sizes, int n_in,
                              void* d_out, int out_size, void* d_ws, size_t ws_size,
                              hipStream_t stream) {
  const float* x  = (const float*)d_in[0];
  const float* gw = (const float*)d_in[1];
  const float* w1 = (const float*)d_in[2];
  const float* w2 = (const float*)d_in[3];
  const float* w3 = (const float*)d_in[4];
  float* out = (float*)d_out;

  const size_t OFF_ROWTOK = 4096;
  const size_t OFF_ROWW   = OFF_ROWTOK + (size_t)CAP_ROWS*4;
  const size_t OFF_TOP    = OFF_ROWW  + (size_t)CAP_ROWS*4;
  const size_t OFF_TOKW   = OFF_TOP   + (size_t)T_TOK*2*4;
  const size_t OFF_XB     = OFF_TOKW  + (size_t)T_TOK*2*4;
  const size_t XB_BYTES   = (size_t)T_TOK*HID*2;                  // 33.55 MB
  const size_t WB       = (size_t)NEXP*FFN_D*HID*2;               // 134.2 MB
  const size_t OFF_W1B  = OFF_XB  + XB_BYTES;
  const size_t OFF_W3B  = OFF_W1B + WB;       // part (2 x 16384 x 2048 bf16 = WB) aliases after up
  const size_t OFF_ACTF = OFF_W3B + WB;
  const size_t ACT_BYTES= (size_t)CAP_ROWS*FFN_D*2;               // 136.3 MB
  const size_t WS_FAST  = OFF_ACTF + ACT_BYTES;                   // ~438.8 MB
  const size_t OFF_W2B  = OFF_ACTF + ACT_BYTES;
  const size_t WS_XL    = OFF_W2B + WB;                           // ~573 MB
  if (ws_size < WS_FAST) return;
  const bool xl = (ws_size >= WS_XL);

  char* ws = (char*)d_ws;
  int*   meta    = (int*)ws;
  int*   row_tok = (int*)(ws + OFF_ROWTOK);
  float* row_w   = (float*)(ws + OFF_ROWW);
  int*   tok_top = (int*)(ws + OFF_TOP);
  float* tok_wt  = (float*)(ws + OFF_TOKW);   // pos_of aliases this after scatter
  u16*   xb      = (u16*)(ws + OFF_XB);
  u16*   w1b     = (u16*)(ws + OFF_W1B);
  u16*   w3b     = (u16*)(ws + OFF_W3B);
  u16*   act     = (u16*)(ws + OFF_ACTF);
  u16*   part    = w3b;                        // w3b dead after up; needs exactly WB bytes
  u16*   w2b     = xl ? (u16*)(ws + OFF_W2B) : w1b;  // separate slot only in XL

  hipMemsetAsync(d_ws, 0, OFF_TOP, stream);   // meta + row_tok + row_w

  // fused front: routing + x->bf16 + w1/w3->bf16 (one launch)
  moe_route  <<<dim3(RT_BLKS + FCVT_BLKS), 256, 0, stream>>>(
      x, gw, meta, tok_top, tok_wt, xb, w1, w1b, w3, w3b);
  moe_prefix <<<1, 1, 0, stream>>>(meta);
  moe_scatter<<<dim3(T_TOK*2/256),    256, 0, stream>>>(tok_top, tok_wt, meta, row_tok, row_w);

  if (xl){
    // w2 cvt rides inside the up launch (tail blocks past NB_UP)
    moe_up_f<<<dim3(NB_UP + CVT_BLKS), 256, 0, stream>>>(
        xb, w1b, w3b, act, meta, row_tok, row_w, w2, w2b);
  } else {
    moe_up_f<<<dim3(NB_UP), 256, 0, stream>>>(
        xb, w1b, w3b, act, meta, row_tok, row_w, w2, w2b);
    moe_cvt <<<dim3(32768), 256, 0, stream>>>(w2, w1b);   // sequential fallback
  }

  moe_down_f<<<dim3(NB_DN), 256, 0, stream>>>(act, w2b, part, meta);
  moe_combine<<<dim3(T_TOK), 256, 0, stream>>>(part, (const int*)tok_wt, out);
}